// Round 1
// baseline (1738.566 us; speedup 1.0000x reference)
//
#include <hip/hip_runtime.h>
#include <math.h>

// ConvSlimCapsule3D fused kernel (fp32 baseline).
// Shapes (fixed): B=2, in_dim=8, in_atoms=16, D=H=W=32, out_dim=8, out_atoms=16, k=3.
// One workgroup handles (b, d, h, w0..w0+7): conv as 64x128x432 GEMM (im2col in LDS),
// then 3 dynamic-routing iterations entirely in LDS, then squash + store.

#define NVOX 8            // voxels (w) per block
#define MROWS 64          // NVOX * in_dim
#define NCOLS 128         // out_dim * out_atoms
#define KTAPS 27
#define BPAD 132          // padded leading dim for B tile (bank-conflict relief)

__global__ __launch_bounds__(256) void caps_fused_kernel(
    const float* __restrict__ x,      // (2,8,16,32,32,32)
    const float* __restrict__ cw,     // (128,16,3,3,3)
    const float* __restrict__ cb,     // (128,)
    const float* __restrict__ bias,   // (8,16,1,1,1)
    float* __restrict__ out)          // (2,8,16,32,32,32)
{
    __shared__ float Atile[KTAPS * MROWS];     // im2col A: [kk][row], 1728 f
    __shared__ float Btile[KTAPS * BPAD];      // weights:  [kk][n],   3564 f
    __shared__ float V[NVOX * 8 * NCOLS];      // votes: [v][i][oc],   8192 f
    __shared__ float LG[NVOX * 8 * 8];         // logits: [v][i][o],    512 f

    const int t = threadIdx.x;
    const int gid = blockIdx.x;
    const int wq = gid & 3;
    const int h  = (gid >> 2) & 31;
    const int d  = (gid >> 7) & 31;
    const int b  = gid >> 12;
    const int w0 = wq * NVOX;

    const int tr = t >> 4;   // 0..15  (4 rows each)
    const int tc = t & 15;   // 0..15  (8 cols each)

    float acc[4][8];
    #pragma unroll
    for (int rr = 0; rr < 4; rr++)
        #pragma unroll
        for (int cc = 0; cc < 8; cc++) acc[rr][cc] = 0.f;

    // zero logits while we're at it
    for (int idx = t; idx < NVOX * 64; idx += 256) LG[idx] = 0.f;

    const float* xb = x + (size_t)b * 8 * 16 * 32768;

    for (int ca = 0; ca < 16; ca++) {
        // ---- stage B: conv_w[n][ca][kk] -> Btile[kk][n] (coalesced global reads) ----
        for (int idx = t; idx < NCOLS * KTAPS; idx += 256) {
            int n  = idx / KTAPS;
            int kk = idx - n * KTAPS;
            Btile[kk * BPAD + n] = cw[n * 432 + ca * KTAPS + kk];
        }
        // ---- stage A (im2col with zero padding): x -> Atile[kk][r] ----
        for (int idx = t; idx < KTAPS * MROWS; idx += 256) {
            int kk = idx >> 6;       // 0..26
            int r  = idx & 63;       // row: i = r>>3, v = r&7
            int i  = r >> 3;
            int v  = r & 7;
            int kz = kk / 9;
            int ky = (kk / 3) % 3;
            int kx = kk % 3;
            int z  = d + kz - 1;
            int y  = h + ky - 1;
            int xw = w0 + v + kx - 1;
            float val = 0.f;
            if ((unsigned)z < 32u && (unsigned)y < 32u && (unsigned)xw < 32u)
                val = xb[(size_t)(i * 16 + ca) * 32768 + z * 1024 + y * 32 + xw];
            Atile[kk * MROWS + r] = val;
        }
        __syncthreads();

        // ---- GEMM micro-kernel: 4x8 per thread ----
        #pragma unroll
        for (int kk = 0; kk < KTAPS; kk++) {
            const float4 a4 = *(const float4*)&Atile[kk * MROWS + tr * 4];
            const float4 b0 = *(const float4*)&Btile[kk * BPAD + tc * 8];
            const float4 b1 = *(const float4*)&Btile[kk * BPAD + tc * 8 + 4];
            const float av[4] = {a4.x, a4.y, a4.z, a4.w};
            const float bv[8] = {b0.x, b0.y, b0.z, b0.w, b1.x, b1.y, b1.z, b1.w};
            #pragma unroll
            for (int rr = 0; rr < 4; rr++)
                #pragma unroll
                for (int cc = 0; cc < 8; cc++)
                    acc[rr][cc] = fmaf(av[rr], bv[cc], acc[rr][cc]);
        }
        __syncthreads();
    }

    // ---- write votes (+ conv bias) into LDS: V[v][i][oc] ----
    float cbv[8];
    #pragma unroll
    for (int cc = 0; cc < 8; cc++) cbv[cc] = cb[tc * 8 + cc];
    #pragma unroll
    for (int rr = 0; rr < 4; rr++) {
        int r = tr * 4 + rr;
        int i = r >> 3;
        int v = r & 7;
        #pragma unroll
        for (int cc = 0; cc < 8; cc++)
            V[(v * 8 + i) * NCOLS + tc * 8 + cc] = acc[rr][cc] + cbv[cc];
    }
    __syncthreads();

    // ---- dynamic routing: 64 active threads, one per (voxel v, out_dim o) ----
    const bool active = (t < 64);
    const int vv = t >> 3;
    const int oo = t & 7;
    const float* Vrow = &V[vv * 8 * NCOLS];

    float bloc[16];
    if (active) {
        #pragma unroll
        for (int a = 0; a < 16; a++) bloc[a] = bias[oo * 16 + a];
    }

    float pre[16];
    #pragma unroll
    for (int a = 0; a < 16; a++) pre[a] = 0.f;

    for (int it = 0; it < 3; it++) {
        float route[8];
        if (active) {
            // softmax over o of LG[v][i][*], evaluated at o = oo, for each i
            #pragma unroll
            for (int i = 0; i < 8; i++) {
                float l[8];
                float m = -1e30f;
                #pragma unroll
                for (int o2 = 0; o2 < 8; o2++) {
                    l[o2] = LG[(vv * 8 + i) * 8 + o2];
                    m = fmaxf(m, l[o2]);
                }
                float s = 0.f;
                #pragma unroll
                for (int o2 = 0; o2 < 8; o2++) s += __expf(l[o2] - m);
                route[i] = __expf(l[oo] - m) / s;
            }
        }
        __syncthreads();   // all LG reads complete before any LG write below

        if (active) {
            // preactivate[o][a] = sum_i votes * route + bias
            #pragma unroll
            for (int a = 0; a < 16; a++) {
                float s = 0.f;
                #pragma unroll
                for (int i = 0; i < 8; i++)
                    s = fmaf(Vrow[i * NCOLS + oo * 16 + a], route[i], s);
                pre[a] = s + bloc[a];
            }
        }

        if (it < 2) {
            if (active) {
                float pn2 = 0.f;
                #pragma unroll
                for (int a = 0; a < 16; a++) pn2 = fmaf(pre[a], pre[a], pn2);
                const float pn = sqrtf(pn2);
                #pragma unroll
                for (int i = 0; i < 8; i++) {
                    float dot = 0.f, vn2 = 0.f;
                    #pragma unroll
                    for (int a = 0; a < 16; a++) {
                        const float vt = Vrow[i * NCOLS + oo * 16 + a];
                        dot = fmaf(pre[a], vt, dot);
                        vn2 = fmaf(vt, vt, vn2);
                    }
                    const float dist = dot / fmaxf(pn * sqrtf(vn2), 1e-8f);
                    LG[(vv * 8 + i) * 8 + oo] += dist;
                }
            }
            __syncthreads();  // LG writes visible before next iteration's reads
        }
    }

    // ---- squash + store ----
    if (active) {
        float n2 = 0.f;
        #pragma unroll
        for (int a = 0; a < 16; a++) n2 = fmaf(pre[a], pre[a], n2);
        const float n = sqrtf(n2);
        const float scale = (n2 / (1.f + n2)) / (n + 1e-12f);
        const size_t sp = (size_t)d * 1024 + h * 32 + (w0 + vv);
        #pragma unroll
        for (int a = 0; a < 16; a++) {
            out[((size_t)((b * 8 + oo) * 16 + a)) * 32768 + sp] = pre[a] * scale;
        }
    }
}

extern "C" void kernel_launch(void* const* d_in, const int* in_sizes, int n_in,
                              void* d_out, int out_size, void* d_ws, size_t ws_size,
                              hipStream_t stream) {
    const float* x    = (const float*)d_in[0];
    const float* cw   = (const float*)d_in[1];
    const float* cb   = (const float*)d_in[2];
    const float* bias = (const float*)d_in[3];
    float* out = (float*)d_out;

    dim3 grid(8192);
    dim3 block(256);
    hipLaunchKernelGGL(caps_fused_kernel, grid, block, 0, stream,
                       x, cw, cb, bias, out);
}

// Round 2
// 909.631 us; speedup vs baseline: 1.9113x; 1.9113x over previous
//
#include <hip/hip_runtime.h>
#include <math.h>

// ConvSlimCapsule3D fused: f16 MFMA conv + LDS routing.
// Shapes fixed: B=2, in_dim=8, in_atoms=16, D=H=W=32, out_dim=8, out_atoms=16, k=3.
// Block = 16 voxels (one (b,d,h,wseg) strip): conv as M=128 x N=128 x K=432 GEMM
// via mfma_f32_16x16x32_f16, K looped as 16 atoms x 32 (taps 27..31 zero-padded
// in BOTH A and the pre-converted weight tensor, so pad contributes exactly 0).

typedef _Float16 half8 __attribute__((ext_vector_type(8)));
typedef float f32x4 __attribute__((ext_vector_type(4)));

#define KPAD 40   // A-tile row stride (f16): 80 B rows -> 20 banks, 16B-aligned frags

// ---- prep: conv_w f32 (128,16,27) -> f16 ws[n][atom][32] with taps 27..31 = 0 ----
__global__ __launch_bounds__(256) void prep_weights(const float* __restrict__ cw,
                                                    _Float16* __restrict__ wh) {
    const int idx = blockIdx.x * 256 + threadIdx.x;   // 65536
    const int n   = idx >> 9;
    const int rem = idx & 511;
    const int ca  = rem >> 5;
    const int tp  = rem & 31;
    float v = 0.0f;
    if (tp < 27) v = cw[n * 432 + ca * 27 + tp];
    wh[idx] = (_Float16)v;
}

__global__ __launch_bounds__(256) void caps_mfma_kernel(
    const float* __restrict__ x,      // (2,8,16,32,32,32) f32
    const _Float16* __restrict__ wh,  // (128,16,32) f16, zero-padded taps
    const float* __restrict__ cb,     // (128,)
    const float* __restrict__ bias,   // (8,16)
    float* __restrict__ out)          // (2,8,16,32,32,32) f32
{
    __shared__ _Float16 Ah[128 * KPAD];      // im2col A chunk [m][k], 10240 B
    __shared__ _Float16 Vh[16 * 8 * 128];    // votes [v][i][oc] f16, 32768 B
    __shared__ float    LG[16 * 8 * 8];      // logits [v][i][o],      4096 B

    const int t    = threadIdx.x;
    const int gid  = blockIdx.x;              // 4096 blocks
    const int wseg = gid & 1;
    const int h    = (gid >> 1) & 31;
    const int d    = (gid >> 6) & 31;
    const int b    = gid >> 11;
    const int w0   = wseg << 4;

    const int wid  = t >> 6;
    const int lane = t & 63;
    const int q    = lane >> 4;   // k-group 0..3
    const int r    = lane & 15;   // row/col within 16-tile
    const int wy   = wid >> 1;    // wave m-half
    const int wx   = wid & 1;     // wave n-half

    for (int i = t; i < 1024; i += 256) LG[i] = 0.f;

    const float* xb = x + (size_t)b * (8 * 16 * 32768);

    // ---- staging precompute: thread t handles m = t>>1, k = (t&1)*16 + jj ----
    const int sm  = t >> 1;       // 0..127
    const int skh = t & 1;        // k half
    const int sid = sm >> 4;      // in_dim
    const int sv  = sm & 15;      // voxel
    int off[16];
    #pragma unroll
    for (int jj = 0; jj < 16; jj++) {
        const int tap = skh * 16 + jj;
        int o = -1;
        if (tap < 27) {
            const int dz = tap / 9, r9 = tap - dz * 9;
            const int dy = r9 / 3,  dx = r9 - dy * 3;
            const int z = d + dz - 1, y = h + dy - 1, w = w0 + sv + dx - 1;
            if ((unsigned)z < 32u && (unsigned)y < 32u && (unsigned)w < 32u)
                o = sid * 524288 + z * 1024 + y * 32 + w;
        }
        off[jj] = o;
    }
    _Float16* Arow = &Ah[sm * KPAD + skh * 16];

    f32x4 acc[4][4];
    #pragma unroll
    for (int i = 0; i < 4; i++)
        #pragma unroll
        for (int j = 0; j < 4; j++) acc[i][j] = (f32x4)0.f;

    // ---- K loop: 16 atoms x K=32 ----
    for (int ca = 0; ca < 16; ca++) {
        const float* xc = xb + ca * 32768;
        half8 t0, t1;
        #pragma unroll
        for (int jj = 0; jj < 8; jj++) {
            const int o = off[jj];
            t0[jj] = (_Float16)((o >= 0) ? xc[o] : 0.0f);
        }
        #pragma unroll
        for (int jj = 0; jj < 8; jj++) {
            const int o = off[8 + jj];
            t1[jj] = (_Float16)((o >= 0) ? xc[o] : 0.0f);
        }
        *(half8*)Arow       = t0;
        *(half8*)(Arow + 8) = t1;
        __syncthreads();

        half8 bf[4], af[4];
        #pragma unroll
        for (int nt = 0; nt < 4; nt++) {
            const int n = wx * 64 + nt * 16 + r;
            bf[nt] = *(const half8*)&wh[n * 512 + ca * 32 + q * 8];
        }
        #pragma unroll
        for (int mt = 0; mt < 4; mt++) {
            const int m = wy * 64 + mt * 16 + r;
            af[mt] = *(const half8*)&Ah[m * KPAD + q * 8];
        }
        #pragma unroll
        for (int mt = 0; mt < 4; mt++)
            #pragma unroll
            for (int nt = 0; nt < 4; nt++)
                acc[mt][nt] = __builtin_amdgcn_mfma_f32_16x16x32_f16(
                    af[mt], bf[nt], acc[mt][nt], 0, 0, 0);
        __syncthreads();
    }

    // ---- epilogue: acc + conv bias -> votes (f16) in LDS ----
    float cbv[4];
    #pragma unroll
    for (int nt = 0; nt < 4; nt++) cbv[nt] = cb[wx * 64 + nt * 16 + r];

    #pragma unroll
    for (int mt = 0; mt < 4; mt++) {
        #pragma unroll
        for (int nt = 0; nt < 4; nt++) {
            const int n = wx * 64 + nt * 16 + r;
            #pragma unroll
            for (int reg = 0; reg < 4; reg++) {
                const int m  = wy * 64 + mt * 16 + q * 4 + reg;  // C/D: row=q*4+reg
                const int id = m >> 4, v = m & 15;
                Vh[(v * 8 + id) * 128 + n] = (_Float16)(acc[mt][nt][reg] + cbv[nt]);
            }
        }
    }
    __syncthreads();

    // ---- dynamic routing: 128 threads, one per (voxel, out_dim) ----
    const bool active = (t < 128);
    const int vv = t & 15;
    const int oo = (t >> 4) & 7;
    const _Float16* Vrow = &Vh[vv * 8 * 128];

    half8 vt[16];   // votes cache: vt[i*2+p] = Vrow[i][oo*16 + p*8 .. +7]
    float bloc[16], pre[16];
    if (active) {
        #pragma unroll
        for (int i = 0; i < 8; i++) {
            vt[i * 2 + 0] = *(const half8*)&Vrow[i * 128 + oo * 16 + 0];
            vt[i * 2 + 1] = *(const half8*)&Vrow[i * 128 + oo * 16 + 8];
        }
        #pragma unroll
        for (int a = 0; a < 16; a++) bloc[a] = bias[oo * 16 + a];
    }
    #pragma unroll
    for (int a = 0; a < 16; a++) pre[a] = 0.f;

    for (int it = 0; it < 3; it++) {
        float route[8];
        if (active) {
            #pragma unroll
            for (int i = 0; i < 8; i++) {
                float l[8], m = -1e30f;
                #pragma unroll
                for (int o2 = 0; o2 < 8; o2++) {
                    l[o2] = LG[vv * 64 + i * 8 + o2];
                    m = fmaxf(m, l[o2]);
                }
                float s = 0.f;
                #pragma unroll
                for (int o2 = 0; o2 < 8; o2++) s += __expf(l[o2] - m);
                route[i] = __expf(l[oo] - m) / s;
            }
        }
        __syncthreads();   // LG reads done before any LG write below

        if (active) {
            #pragma unroll
            for (int a = 0; a < 16; a++) {
                float s = 0.f;
                #pragma unroll
                for (int i = 0; i < 8; i++)
                    s = fmaf((float)vt[i * 2 + (a >> 3)][a & 7], route[i], s);
                pre[a] = s + bloc[a];
            }
        }

        if (it < 2) {
            if (active) {
                float pn2 = 0.f;
                #pragma unroll
                for (int a = 0; a < 16; a++) pn2 = fmaf(pre[a], pre[a], pn2);
                const float pn = sqrtf(pn2);
                #pragma unroll
                for (int i = 0; i < 8; i++) {
                    float dot = 0.f, vn2 = 0.f;
                    #pragma unroll
                    for (int a = 0; a < 16; a++) {
                        const float v2 = (float)vt[i * 2 + (a >> 3)][a & 7];
                        dot = fmaf(pre[a], v2, dot);
                        vn2 = fmaf(v2, v2, vn2);
                    }
                    const float dist = dot / fmaxf(pn * sqrtf(vn2), 1e-8f);
                    LG[vv * 64 + i * 8 + oo] += dist;
                }
            }
            __syncthreads();  // LG writes visible before next iter's reads
        }
    }

    // ---- squash + store ----
    if (active) {
        float n2 = 0.f;
        #pragma unroll
        for (int a = 0; a < 16; a++) n2 = fmaf(pre[a], pre[a], n2);
        const float n = sqrtf(n2);
        const float scale = (n2 / (1.f + n2)) / (n + 1e-12f);
        const size_t sp = (size_t)d * 1024 + h * 32 + (w0 + vv);
        #pragma unroll
        for (int a = 0; a < 16; a++)
            out[((size_t)((b * 8 + oo) * 16 + a)) * 32768 + sp] = pre[a] * scale;
    }
}

extern "C" void kernel_launch(void* const* d_in, const int* in_sizes, int n_in,
                              void* d_out, int out_size, void* d_ws, size_t ws_size,
                              hipStream_t stream) {
    const float* x    = (const float*)d_in[0];
    const float* cw   = (const float*)d_in[1];
    const float* cb   = (const float*)d_in[2];
    const float* bias = (const float*)d_in[3];
    float* out = (float*)d_out;
    _Float16* wh = (_Float16*)d_ws;   // 128*512*2 = 131072 B

    hipLaunchKernelGGL(prep_weights, dim3(256), dim3(256), 0, stream, cw, wh);
    hipLaunchKernelGGL(caps_mfma_kernel, dim3(4096), dim3(256), 0, stream,
                       x, wh, cb, bias, out);
}

// Round 4
// 317.192 us; speedup vs baseline: 5.4811x; 2.8678x over previous
//
#include <hip/hip_runtime.h>
#include <math.h>

// ConvSlimCapsule3D fused, round 4: round-3 structure with NO slab overlay.
// Shapes fixed: B=2, in_dim=8, in_atoms=16, D=H=W=32, out_dim=8, out_atoms=16, k=3.
// Block = 16 voxels (b,d,h,wseg): raw x slab (10zy x 18w x 128ch f16, swizzled)
// staged once to LDS; conv = M128 x N128 x K448 GEMM (14 chunks x 32) with
// barrier-free K-loop (A from slab, B from pre-reordered f16 weights in global).
// Votes live in their OWN LDS region (slab never written after staging); RT/LG
// overlay the votes region only after votes are cached in registers (vf).

typedef _Float16 half8 __attribute__((ext_vector_type(8)));
typedef float f32x4 __attribute__((ext_vector_type(4)));

// ---- prep: cw f32 (n=128, ca=16, tap=27) -> wh2 f16 [n][c=14][k=32], k = tp*16+ca,
//      tap = 2c+tp, tap 27 zeroed (matches A-side zero row). ----
__global__ __launch_bounds__(256) void prep_weights(const float* __restrict__ cw,
                                                    _Float16* __restrict__ wh2) {
    const int idx = blockIdx.x * 256 + threadIdx.x;   // 57344
    const int n   = idx / 448;
    const int rem = idx - n * 448;
    const int c   = rem >> 5;
    const int k   = rem & 31;
    const int tp  = k >> 4, ca = k & 15;
    const int tap = 2 * c + tp;
    float v = (tap < 27) ? cw[n * 432 + ca * 27 + tap] : 0.0f;
    wh2[idx] = (_Float16)v;
}

// slab byte offset: [zy 0..9][j 0..17][unit 0..15]*16B, unit swizzled by j
__device__ __forceinline__ int slab_off_b(int zy, int j, int ch) {
    const int u = ch >> 3;
    return zy * 4608 + j * 256 + ((u ^ (j & 15)) << 4) + ((ch & 7) << 1);
}

__global__ __launch_bounds__(256, 2) void caps_mfma_kernel(
    const float* __restrict__ x,      // (2,8,16,32,32,32) f32
    const _Float16* __restrict__ wh2, // (128,14,32) f16 reordered
    const float* __restrict__ cb,     // (128,)
    const float* __restrict__ bias,   // (8,16)
    float* __restrict__ out)          // (2,8,16,32,32,32) f32
{
    __shared__ half8 slabv[2880];     // 46080 B: x slab (read-only after staging)
    __shared__ half8 vhv[2064];       // 33024 B: votes; RT/LG overlay when dead
    char* smem = (char*)slabv;
    _Float16* Vh = (_Float16*)vhv;
    float* RT = (float*)vhv;          // bytes 0..4607 of vote region
    float* LG = (float*)vhv + 1152;   // bytes 4608..9215

    const int t    = threadIdx.x;
    const int gid  = blockIdx.x;              // 4096
    const int wseg = gid & 1;
    const int h    = (gid >> 1) & 31;
    const int d    = (gid >> 6) & 31;
    const int b    = gid >> 11;
    const int w0g  = wseg << 4;

    const float* xb = x + (size_t)b * 4194304;

    // ================= stage slab: 1280 rows (zy 0..9 x ch 0..127) x 5 segs =========
    for (int rrd = 0; rrd < 25; rrd++) {
        const int sid = t + rrd * 256;        // 0..6399
        const int row = sid / 5;
        const int seg = sid - row * 5;        // 0..4
        const int zyr = row >> 7;             // 0..9 (9 = zero row)
        const int ch  = row & 127;
        const int dz  = zyr / 3;
        const int dy  = zyr - dz * 3;
        const int z   = d + dz - 1;
        const int y   = h + dy - 1;
        const bool rv = (zyr < 9) && ((unsigned)z < 32u) && ((unsigned)y < 32u);
        if (seg < 4) {
            f32x4 val = (f32x4)0.f;
            if (rv) {
                const float* rp = xb + (size_t)ch * 32768 + z * 1024 + y * 32;
                val = *(const f32x4*)(rp + w0g + seg * 4);   // 16B aligned
            }
            #pragma unroll
            for (int e = 0; e < 4; e++) {
                const int j = seg * 4 + 1 + e;               // j = 1..16
                *(_Float16*)(smem + slab_off_b(zyr, j, ch)) = (_Float16)val[e];
            }
        } else {
            // scalar edge element + the zero-pad element
            const int wsc = (w0g == 0) ? 16 : 15;
            const int jsc = (w0g == 0) ? 17 : 0;
            const int jz  = (w0g == 0) ? 0  : 17;
            float v = 0.f;
            if (rv) v = xb[(size_t)ch * 32768 + z * 1024 + y * 32 + wsc];
            *(_Float16*)(smem + slab_off_b(zyr, jsc, ch)) = (_Float16)v;
            *(_Float16*)(smem + slab_off_b(zyr, jz,  ch)) = (_Float16)0.f;
        }
    }
    __syncthreads();   // B0: slab fully staged

    // ================= GEMM: M=128, N=128, K=448 (14 chunks), no inner barriers ====
    const int wid = t >> 6, lane = t & 63;
    const int q = lane >> 4, r = lane & 15;
    const int wy = wid >> 1, wx = wid & 1;
    const int qlow = q & 1, tphase = q >> 1;

    int zyA[14], dxA[14];
    #pragma unroll
    for (int c = 0; c < 14; c++) {
        const int tap = 2 * c + tphase;       // 0..27; tap 27 -> zy 9 (zero row)
        const int dz = tap / 9, r9 = tap - dz * 9;
        const int dy = r9 / 3,  dxx = r9 - dy * 3;
        zyA[c] = dz * 3 + dy;
        dxA[c] = dxx;
    }
    int uA[4];
    #pragma unroll
    for (int mt = 0; mt < 4; mt++) uA[mt] = (wy * 4 + mt) * 2 + qlow;

    const _Float16* bp[4];
    #pragma unroll
    for (int nt = 0; nt < 4; nt++)
        bp[nt] = wh2 + (wx * 64 + nt * 16 + r) * 448 + q * 8;

    f32x4 acc[4][4];
    #pragma unroll
    for (int i = 0; i < 4; i++)
        #pragma unroll
        for (int j = 0; j < 4; j++) acc[i][j] = (f32x4)0.f;

    #pragma unroll
    for (int c = 0; c < 14; c++) {
        half8 bf[4], af[4];
        #pragma unroll
        for (int nt = 0; nt < 4; nt++)
            bf[nt] = *(const half8*)(bp[nt] + c * 32);
        const int jw = r + dxA[c];
        const int rowb = zyA[c] * 4608 + jw * 256;
        const int js = jw & 15;
        #pragma unroll
        for (int mt = 0; mt < 4; mt++)
            af[mt] = *(const half8*)(smem + rowb + ((uA[mt] ^ js) << 4));
        #pragma unroll
        for (int mt = 0; mt < 4; mt++)
            #pragma unroll
            for (int nt = 0; nt < 4; nt++)
                acc[mt][nt] = __builtin_amdgcn_mfma_f32_16x16x32_f16(
                    af[mt], bf[nt], acc[mt][nt], 0, 0, 0);
    }

    // ================= epilogue: votes (+conv bias) f16 into OWN region ============
    // (disjoint from slab -> no barrier needed vs other waves' K-loop reads)
    float cbv[4];
    #pragma unroll
    for (int nt = 0; nt < 4; nt++) cbv[nt] = cb[wx * 64 + nt * 16 + r];
    #pragma unroll
    for (int mt = 0; mt < 4; mt++) {
        #pragma unroll
        for (int nt = 0; nt < 4; nt++) {
            const int n = wx * 64 + nt * 16 + r;
            #pragma unroll
            for (int reg = 0; reg < 4; reg++) {
                const int v = q * 4 + reg;          // C/D row = q*4+reg
                const int i = wy * 4 + mt;
                Vh[v * 1032 + i * 128 + n] = (_Float16)(acc[mt][nt][reg] + cbv[nt]);
            }
        }
    }
    __syncthreads();   // B2: all vote writes visible

    // ================= routing: 256 threads = 128 (v,o) pairs x 2 halves ===========
    const int p = t >> 1, half = t & 1;
    const int vv = p & 15, oo = p >> 4;   // also coop-softmax task (v2=vv, i2=oo)

    float vf[8][8];
    #pragma unroll
    for (int i = 0; i < 8; i++) {
        const half8 hv = *(const half8*)&Vh[vv * 1032 + i * 128 + oo * 16 + half * 8];
        #pragma unroll
        for (int a = 0; a < 8; a++) vf[i][a] = (float)hv[a];
    }
    __syncthreads();   // B3: vote reads done -> RT/LG may overlay vote region

    float vn[8];
    #pragma unroll
    for (int i = 0; i < 8; i++) {
        float s = 0.f;
        #pragma unroll
        for (int a = 0; a < 8; a++) s = fmaf(vf[i][a], vf[i][a], s);
        const float so = __shfl_xor(s, 1);
        vn[i] = sqrtf(s + so);
    }
    float bl[8];
    #pragma unroll
    for (int a = 0; a < 8; a++) bl[a] = bias[oo * 16 + half * 8 + a];

    float rt[8], lgr[8], pre[8];
    #pragma unroll
    for (int i = 0; i < 8; i++) { rt[i] = 0.125f; lgr[i] = 0.f; }

    for (int it = 0; it < 3; it++) {
        #pragma unroll
        for (int a = 0; a < 8; a++) {
            float s = bl[a];
            #pragma unroll
            for (int i = 0; i < 8; i++) s = fmaf(rt[i], vf[i][a], s);
            pre[a] = s;
        }
        if (it == 2) break;

        float s2 = 0.f;
        #pragma unroll
        for (int a = 0; a < 8; a++) s2 = fmaf(pre[a], pre[a], s2);
        const float pn = sqrtf(s2 + __shfl_xor(s2, 1));

        #pragma unroll
        for (int i = 0; i < 8; i++) {
            float dp = 0.f;
            #pragma unroll
            for (int a = 0; a < 8; a++) dp = fmaf(pre[a], vf[i][a], dp);
            const float dot = dp + __shfl_xor(dp, 1);
            lgr[i] += dot / fmaxf(pn * vn[i], 1e-8f);
        }
        if (half == 0) {
            #pragma unroll
            for (int i = 0; i < 8; i++) LG[vv * 72 + i * 8 + oo] = lgr[i];
        }
        __syncthreads();   // LG writes visible

        // coop softmax over o for task (v2=vv, i2=oo); |logit| <= 2 -> no max-sub
        {
            const f32x4 E = *(const f32x4*)&LG[vv * 72 + oo * 8 + half * 4];
            f32x4 ex; float ps = 0.f;
            #pragma unroll
            for (int k = 0; k < 4; k++) { ex[k] = __expf(E[k]); ps += ex[k]; }
            const float sum = ps + __shfl_xor(ps, 1);
            const float rs = 1.f / sum;
            f32x4 w4;
            #pragma unroll
            for (int k = 0; k < 4; k++) w4[k] = ex[k] * rs;
            *(f32x4*)&RT[vv * 72 + oo * 8 + half * 4] = w4;
        }
        __syncthreads();   // RT writes visible

        #pragma unroll
        for (int i = 0; i < 8; i++) rt[i] = RT[vv * 72 + i * 8 + oo];
    }

    // ---- squash + store ----
    float s2 = 0.f;
    #pragma unroll
    for (int a = 0; a < 8; a++) s2 = fmaf(pre[a], pre[a], s2);
    const float n2 = s2 + __shfl_xor(s2, 1);
    const float nn = sqrtf(n2);
    const float scale = (n2 / (1.f + n2)) / (nn + 1e-12f);
    const size_t sp = (size_t)d * 1024 + h * 32 + w0g + vv;
    #pragma unroll
    for (int a = 0; a < 8; a++)
        out[((size_t)((b * 8 + oo) * 16 + half * 8 + a)) * 32768 + sp] = pre[a] * scale;
}

extern "C" void kernel_launch(void* const* d_in, const int* in_sizes, int n_in,
                              void* d_out, int out_size, void* d_ws, size_t ws_size,
                              hipStream_t stream) {
    const float* x    = (const float*)d_in[0];
    const float* cw   = (const float*)d_in[1];
    const float* cb   = (const float*)d_in[2];
    const float* bias = (const float*)d_in[3];
    float* out = (float*)d_out;
    _Float16* wh2 = (_Float16*)d_ws;   // 57344 * 2 = 114688 B

    hipLaunchKernelGGL(prep_weights, dim3(224), dim3(256), 0, stream, cw, wh2);
    hipLaunchKernelGGL(caps_mfma_kernel, dim3(4096), dim3(256), 0, stream,
                       x, wh2, cb, bias, out);
}